// Round 1
// baseline (1238.649 us; speedup 1.0000x reference)
//
#include <hip/hip_runtime.h>
#include <hip/hip_bf16.h>

#define BN_RSQ 0.9999950000374997f  // 1/sqrt(1+1e-5)

// ---------------------------------------------------------------------------
// Generic 3x3 SAME conv + BN(eval) + ReLU.
//   - CIN1 channels from in1, CIN2 channels from in2 (fused concat).
//   - POOL_IN: input coords are pooled dims; loader does 2x2 maxpool on the fly
//     (in1 has dims [B, CIN1, 2H, 2W]).
//   - FUSE_OUT: apply 1x1 conv (wout/bout) + sigmoid, write single channel.
// Block: 256 threads = 16x16 output pixels. Grid: (W/16, H/16, B).
// ---------------------------------------------------------------------------
template <int CIN1, int CIN2, int COUT, bool POOL_IN, bool FUSE_OUT>
__launch_bounds__(256)
__global__ void conv3x3_cbr(const float* __restrict__ in1,
                            const float* __restrict__ in2,
                            const float* __restrict__ wgt,
                            const float* __restrict__ bias,
                            const float* __restrict__ gam,
                            const float* __restrict__ alp,
                            const float* __restrict__ wout,
                            const float* __restrict__ bout,
                            float* __restrict__ out, int H, int W) {
  constexpr int CIN = CIN1 + CIN2;
  constexpr int T = 16;
  constexpr int CHUNK = (CIN < 8) ? CIN : 8;

  __shared__ float tile[CHUNK][T + 2][T + 3];  // x padded to 19 (conflict-safe)

  const int tx = threadIdx.x & 15;
  const int ty = threadIdx.x >> 4;
  const int gx0 = blockIdx.x * T;
  const int gy0 = blockIdx.y * T;
  const int b = blockIdx.z;

  float acc[COUT];
#pragma unroll
  for (int o = 0; o < COUT; ++o) acc[o] = 0.f;

  for (int cc = 0; cc < CIN; cc += CHUNK) {
    __syncthreads();
    // ---- load CHUNK channels of an 18x18 halo tile ----
    for (int idx = threadIdx.x; idx < CHUNK * (T + 2) * (T + 2); idx += 256) {
      int c = idx / ((T + 2) * (T + 2));
      int r = idx - c * ((T + 2) * (T + 2));
      int yy = r / (T + 2);
      int xx = r - yy * (T + 2);
      int iy = gy0 + yy - 1;
      int ix = gx0 + xx - 1;
      int cg = cc + c;
      float v = 0.f;
      if (iy >= 0 && iy < H && ix >= 0 && ix < W) {
        const float* src;
        int cbase;
        if (CIN2 == 0 || cg < CIN1) {
          src = in1;
          cbase = b * CIN1 + cg;
        } else {
          src = in2;
          cbase = b * CIN2 + (cg - CIN1);
        }
        if (POOL_IN) {
          const float* p = src + (cbase * (2 * H) + 2 * iy) * (2 * W) + 2 * ix;
          float v0 = p[0], v1 = p[1], v2 = p[2 * W], v3 = p[2 * W + 1];
          v = fmaxf(fmaxf(v0, v1), fmaxf(v2, v3));
        } else {
          v = src[(cbase * H + iy) * W + ix];
        }
      }
      tile[c][yy][xx] = v;
    }
    __syncthreads();
    // ---- accumulate ----
#pragma unroll
    for (int c = 0; c < CHUNK; ++c) {
      float v00 = tile[c][ty + 0][tx + 0], v01 = tile[c][ty + 0][tx + 1], v02 = tile[c][ty + 0][tx + 2];
      float v10 = tile[c][ty + 1][tx + 0], v11 = tile[c][ty + 1][tx + 1], v12 = tile[c][ty + 1][tx + 2];
      float v20 = tile[c][ty + 2][tx + 0], v21 = tile[c][ty + 2][tx + 1], v22 = tile[c][ty + 2][tx + 2];
      const int cg = cc + c;
#pragma unroll
      for (int o = 0; o < COUT; ++o) {
        const float* w = wgt + (o * CIN + cg) * 9;  // uniform -> scalar loads
        float s = acc[o];
        s = fmaf(v00, w[0], s); s = fmaf(v01, w[1], s); s = fmaf(v02, w[2], s);
        s = fmaf(v10, w[3], s); s = fmaf(v11, w[4], s); s = fmaf(v12, w[5], s);
        s = fmaf(v20, w[6], s); s = fmaf(v21, w[7], s); s = fmaf(v22, w[8], s);
        acc[o] = s;
      }
    }
  }

  const int ox = gx0 + tx;
  const int oy = gy0 + ty;
  if (FUSE_OUT) {
    float s = bout[0];
#pragma unroll
    for (int o = 0; o < COUT; ++o) {
      float r = fmaxf((acc[o] + bias[o]) * (gam[o] * BN_RSQ) + alp[o], 0.f);
      s = fmaf(r, wout[o], s);
    }
    out[(b * H + oy) * W + ox] = 1.f / (1.f + __expf(-s));
  } else {
#pragma unroll
    for (int o = 0; o < COUT; ++o) {
      float r = fmaxf((acc[o] + bias[o]) * (gam[o] * BN_RSQ) + alp[o], 0.f);
      out[((b * COUT + o) * H + oy) * W + ox] = r;
    }
  }
}

// ---------------------------------------------------------------------------
// Bilinear 2x upsample, align_corners=True. Block (16,16), grid (Wo/16,Ho/16,B*C)
// ---------------------------------------------------------------------------
__global__ void up2_kernel(const float* __restrict__ in, float* __restrict__ out,
                           int Hi, int Wi) {
  const int Ho = 2 * Hi, Wo = 2 * Wi;
  const int ox = blockIdx.x * 16 + threadIdx.x;
  const int oy = blockIdx.y * 16 + threadIdx.y;
  const int bc = blockIdx.z;
  const float sy = (float)((double)(Hi - 1) / (double)(Ho - 1));
  const float sx = (float)((double)(Wi - 1) / (double)(Wo - 1));
  float fy = oy * sy, fx = ox * sx;
  int y0 = (int)floorf(fy); int y1 = min(y0 + 1, Hi - 1);
  int x0 = (int)floorf(fx); int x1 = min(x0 + 1, Wi - 1);
  float wy = fy - (float)y0, wx = fx - (float)x0;
  const float* p = in + bc * Hi * Wi;
  float a00 = p[y0 * Wi + x0], a01 = p[y0 * Wi + x1];
  float a10 = p[y1 * Wi + x0], a11 = p[y1 * Wi + x1];
  float r0 = a00 * (1.f - wy) + a10 * wy;   // y first (matches reference)
  float r1 = a01 * (1.f - wy) + a11 * wy;
  out[(bc * Ho + oy) * Wo + ox] = r0 * (1.f - wx) + r1 * wx;
}

// ---------------------------------------------------------------------------
// FCAS: for each element v of the 64x64 channel, count p=#(>v), n=#(==v),
// e=#(<v) over all 4096 elements. Interior pixels -> (p*w0+b0+n*w1+b1+e*w2+b2)/3
// ---------------------------------------------------------------------------
__global__ void fcas_count_kernel(const float* __restrict__ ch,
                                  const float* __restrict__ w,
                                  const float* __restrict__ bb,
                                  float* __restrict__ scratch) {
  const int H = 64, W = 64, N = H * W;
  __shared__ float vals[N];
  for (int i = threadIdx.x; i < N; i += blockDim.x) vals[i] = ch[i];
  __syncthreads();
  int idx = blockIdx.x * blockDim.x + threadIdx.x;
  if (idx >= N) return;
  float v = vals[idx];
  int p = 0, n = 0, e = 0;
  for (int k = 0; k < N; ++k) {
    float u = vals[k];
    p += (u > v);
    n += (u == v);
    e += (u < v);
  }
  float val = ((float)p * w[0] + bb[0] + (float)n * w[1] + bb[1] +
               (float)e * w[2] + bb[2]) / 3.0f;
  int i = idx >> 6, j = idx & 63;
  bool interior = (i >= 1) && (i <= H - 2) && (j >= 1) && (j <= W - 2);
  scratch[idx] = interior ? val : v;
}

__global__ void fcas_copy_kernel(const float* __restrict__ scratch,
                                 float* __restrict__ ch) {
  int i = blockIdx.x * 256 + threadIdx.x;
  if (i < 4096) ch[i] = scratch[i];
}

// ---------------------------------------------------------------------------
extern "C" void kernel_launch(void* const* d_in, const int* in_sizes, int n_in,
                              void* d_out, int out_size, void* d_ws, size_t ws_size,
                              hipStream_t stream) {
  const float* x      = (const float*)d_in[0];
  const float* w_inc  = (const float*)d_in[1];
  const float* b_inc  = (const float*)d_in[2];
  const float* g_inc  = (const float*)d_in[3];
  const float* a_inc  = (const float*)d_in[4];
  const float* w_d1   = (const float*)d_in[5];
  const float* b_d1   = (const float*)d_in[6];
  const float* g_d1   = (const float*)d_in[7];
  const float* a_d1   = (const float*)d_in[8];
  const float* w_d2   = (const float*)d_in[9];
  const float* b_d2   = (const float*)d_in[10];
  const float* g_d2   = (const float*)d_in[11];
  const float* a_d2   = (const float*)d_in[12];
  const float* w_d3   = (const float*)d_in[13];
  const float* b_d3   = (const float*)d_in[14];
  const float* g_d3   = (const float*)d_in[15];
  const float* a_d3   = (const float*)d_in[16];
  const float* w_u2   = (const float*)d_in[17];
  const float* b_u2   = (const float*)d_in[18];
  const float* g_u2   = (const float*)d_in[19];
  const float* a_u2   = (const float*)d_in[20];
  const float* w_u3   = (const float*)d_in[21];
  const float* b_u3   = (const float*)d_in[22];
  const float* g_u3   = (const float*)d_in[23];
  const float* a_u3   = (const float*)d_in[24];
  const float* w_u4   = (const float*)d_in[25];
  const float* b_u4   = (const float*)d_in[26];
  const float* g_u4   = (const float*)d_in[27];
  const float* a_u4   = (const float*)d_in[28];
  const float* w_out  = (const float*)d_in[29];
  const float* b_out  = (const float*)d_in[30];
  const float* fcas_w = (const float*)d_in[31];
  const float* fcas_b = (const float*)d_in[32];

  float* ws = (float*)d_ws;
  // workspace layout (floats)
  float* x1 = ws;                      // 8*8*512*512   = 16,777,216
  float* x2 = x1 + 16777216;           // 8*16*256*256  =  8,388,608
  float* x3 = x2 + 8388608;            // 8*32*128*128  =  4,194,304
  float* x4 = x3 + 4194304;            // 8*32*64*64    =  1,048,576
  float* up = x4 + 1048576;            // max 8*8*512*512 = 16,777,216
  float* uo = up + 16777216;           // max 8*8*256*256 = 4,194,304 (u2out/u3out)
  float* fs = uo + 4194304;            // 4096
  float* outp = (float*)d_out;

  dim3 blk(256);
  dim3 blk2(16, 16);

  // K1: inc  conv 3->8 @512
  conv3x3_cbr<3, 0, 8, false, false><<<dim3(32, 32, 8), blk, 0, stream>>>(
      x, nullptr, w_inc, b_inc, g_inc, a_inc, nullptr, nullptr, x1, 512, 512);
  // K2: d1   pool(x1) -> conv 8->16 @256
  conv3x3_cbr<8, 0, 16, true, false><<<dim3(16, 16, 8), blk, 0, stream>>>(
      x1, nullptr, w_d1, b_d1, g_d1, a_d1, nullptr, nullptr, x2, 256, 256);
  // K3: d2   pool(x2) -> conv 16->32 @128
  conv3x3_cbr<16, 0, 32, true, false><<<dim3(8, 8, 8), blk, 0, stream>>>(
      x2, nullptr, w_d2, b_d2, g_d2, a_d2, nullptr, nullptr, x3, 128, 128);
  // K4: d3   pool(x3) -> conv 32->32 @64
  conv3x3_cbr<32, 0, 32, true, false><<<dim3(4, 4, 8), blk, 0, stream>>>(
      x3, nullptr, w_d3, b_d3, g_d3, a_d3, nullptr, nullptr, x4, 64, 64);
  // K5/K6: FCAS on x4[0,1]
  fcas_count_kernel<<<dim3(16), blk, 0, stream>>>(x4 + 4096, fcas_w, fcas_b, fs);
  fcas_copy_kernel<<<dim3(16), blk, 0, stream>>>(fs, x4 + 4096);
  // K7: up2(x4) @64->128 (8*32 maps)
  up2_kernel<<<dim3(8, 8, 256), blk2, 0, stream>>>(x4, up, 64, 64);
  // K8: u2   conv cat(x3, up) 64->16 @128
  conv3x3_cbr<32, 32, 16, false, false><<<dim3(8, 8, 8), blk, 0, stream>>>(
      x3, up, w_u2, b_u2, g_u2, a_u2, nullptr, nullptr, uo, 128, 128);
  // K9: up2(u2out) @128->256 (8*16 maps)
  up2_kernel<<<dim3(16, 16, 128), blk2, 0, stream>>>(uo, up, 128, 128);
  // K10: u3  conv cat(x2, up) 32->8 @256
  conv3x3_cbr<16, 16, 8, false, false><<<dim3(16, 16, 8), blk, 0, stream>>>(
      x2, up, w_u3, b_u3, g_u3, a_u3, nullptr, nullptr, uo, 256, 256);
  // K11: up2(u3out) @256->512 (8*8 maps)
  up2_kernel<<<dim3(32, 32, 64), blk2, 0, stream>>>(uo, up, 256, 256);
  // K12: u4  conv cat(x1, up) 16->4 @512, fused 1x1 conv + sigmoid
  conv3x3_cbr<8, 8, 4, false, true><<<dim3(32, 32, 8), blk, 0, stream>>>(
      x1, up, w_u4, b_u4, g_u4, a_u4, w_out, b_out, outp, 512, 512);
}

// Round 2
// 1021.742 us; speedup vs baseline: 1.2123x; 1.2123x over previous
//
#include <hip/hip_runtime.h>
#include <hip/hip_bf16.h>

#define BN_RSQ 0.9999950000374997f  // 1/sqrt(1+1e-5)

// ---------------------------------------------------------------------------
// Prefold BN into conv weights: wf = w*g*rsq, bf = b*g*rsq + a.
// One launch covers all 7 layers (blockIdx.y = layer).
// ---------------------------------------------------------------------------
struct LayerP {
  const float* w; const float* b; const float* g; const float* a;
  float* wf; float* bf; int cout; int cin;
};
struct AllP { LayerP L[7]; };

__global__ void prefold_kernel(AllP A) {
  LayerP p = A.L[blockIdx.y];
  int n = p.cout * p.cin * 9;
  int i = blockIdx.x * 256 + threadIdx.x;
  if (i < n) {
    int o = i / (p.cin * 9);
    p.wf[i] = p.w[i] * p.g[o] * BN_RSQ;
  }
  if (i < p.cout) p.bf[i] = p.b[i] * p.g[i] * BN_RSQ + p.a[i];
}

// ---------------------------------------------------------------------------
// 3x3 SAME conv (+folded BN) + ReLU.
//   - CIN1 channels from in1, CIN2 from in2 (fused concat).
//   - POOL_IN: loader does 2x2 maxpool on the fly (in1/in2 dims [.,.,2H,2W]).
//   - OSPLIT: output channels split across blocks (blockIdx.z = og*8 + b).
//   - FUSE_OUT (requires OSPLIT==1): 1x1 conv + sigmoid epilogue.
// Weights are staged into LDS per channel-chunk and read as uniform-address
// broadcast ds_read_b128 (no scalar loads in the inner loop -> no lgkmcnt
// full-drain serialization).
// Block: 256 threads = 16x16 output pixels.
// ---------------------------------------------------------------------------
template <int CIN1, int CIN2, int COUTG, int OSPLIT, bool POOL_IN, bool FUSE_OUT>
__launch_bounds__(256)
__global__ void conv3x3_cbr(const float* __restrict__ in1,
                            const float* __restrict__ in2,
                            const float* __restrict__ wf,
                            const float* __restrict__ bf,
                            const float* __restrict__ wout,
                            const float* __restrict__ bout,
                            float* __restrict__ out, int H, int W) {
  constexpr int CIN = CIN1 + CIN2;
  constexpr int COUT = COUTG * OSPLIT;
  constexpr int T = 16;
  constexpr int CHUNK = (CIN < 8) ? CIN : 8;
  constexpr int WS = 12;  // weight stride (12 floats -> 16B-aligned float4s)

  __shared__ float tile[CHUNK][T + 2][T + 3];  // x padded (conflict-safe)
  __shared__ float wsm[COUTG * CHUNK * WS];

  const int tx = threadIdx.x & 15;
  const int ty = threadIdx.x >> 4;
  const int gx0 = blockIdx.x * T;
  const int gy0 = blockIdx.y * T;
  const int b = blockIdx.z & 7;
  const int og = blockIdx.z >> 3;
  const int obase = og * COUTG;

  float acc[COUTG];
#pragma unroll
  for (int o = 0; o < COUTG; ++o) acc[o] = 0.f;

  for (int cc = 0; cc < CIN; cc += CHUNK) {
    __syncthreads();
    // ---- stage this chunk's weights into LDS ----
    for (int idx = threadIdx.x; idx < COUTG * CHUNK * 9; idx += 256) {
      int o = idx / (CHUNK * 9);
      int r = idx - o * (CHUNK * 9);
      int c = r / 9;
      int t = r - c * 9;
      wsm[(o * CHUNK + c) * WS + t] = wf[((obase + o) * CIN + cc + c) * 9 + t];
    }
    // ---- load CHUNK channels of an 18x18 halo tile ----
    for (int idx = threadIdx.x; idx < CHUNK * (T + 2) * (T + 2); idx += 256) {
      int c = idx / ((T + 2) * (T + 2));
      int r = idx - c * ((T + 2) * (T + 2));
      int yy = r / (T + 2);
      int xx = r - yy * (T + 2);
      int iy = gy0 + yy - 1;
      int ix = gx0 + xx - 1;
      int cg = cc + c;
      float v = 0.f;
      if (iy >= 0 && iy < H && ix >= 0 && ix < W) {
        const float* src;
        int cbase;
        if (CIN2 == 0 || cg < CIN1) {
          src = in1;
          cbase = b * CIN1 + cg;
        } else {
          src = in2;
          cbase = b * CIN2 + (cg - CIN1);
        }
        if (POOL_IN) {
          const float* p = src + (cbase * (2 * H) + 2 * iy) * (2 * W) + 2 * ix;
          float v0 = p[0], v1 = p[1], v2 = p[2 * W], v3 = p[2 * W + 1];
          v = fmaxf(fmaxf(v0, v1), fmaxf(v2, v3));
        } else {
          v = src[(cbase * H + iy) * W + ix];
        }
      }
      tile[c][yy][xx] = v;
    }
    __syncthreads();
    // ---- accumulate: pure LDS reads + FMAs ----
#pragma unroll
    for (int c = 0; c < CHUNK; ++c) {
      float v00 = tile[c][ty + 0][tx + 0], v01 = tile[c][ty + 0][tx + 1], v02 = tile[c][ty + 0][tx + 2];
      float v10 = tile[c][ty + 1][tx + 0], v11 = tile[c][ty + 1][tx + 1], v12 = tile[c][ty + 1][tx + 2];
      float v20 = tile[c][ty + 2][tx + 0], v21 = tile[c][ty + 2][tx + 1], v22 = tile[c][ty + 2][tx + 2];
#pragma unroll
      for (int o = 0; o < COUTG; ++o) {
        const float4* wp = (const float4*)&wsm[(o * CHUNK + c) * WS];
        float4 wa = wp[0];
        float4 wb = wp[1];
        float w8 = wsm[(o * CHUNK + c) * WS + 8];
        float s = acc[o];
        s = fmaf(v00, wa.x, s); s = fmaf(v01, wa.y, s); s = fmaf(v02, wa.z, s);
        s = fmaf(v10, wa.w, s); s = fmaf(v11, wb.x, s); s = fmaf(v12, wb.y, s);
        s = fmaf(v20, wb.z, s); s = fmaf(v21, wb.w, s); s = fmaf(v22, w8, s);
        acc[o] = s;
      }
    }
  }

  const int ox = gx0 + tx;
  const int oy = gy0 + ty;
  if (FUSE_OUT) {
    float s = bout[0];
#pragma unroll
    for (int o = 0; o < COUTG; ++o) {
      float r = fmaxf(acc[o] + bf[obase + o], 0.f);
      s = fmaf(r, wout[o], s);
    }
    out[(b * H + oy) * W + ox] = 1.f / (1.f + __expf(-s));
  } else {
#pragma unroll
    for (int o = 0; o < COUTG; ++o) {
      float r = fmaxf(acc[o] + bf[obase + o], 0.f);
      out[((b * COUT + obase + o) * H + oy) * W + ox] = r;
    }
  }
}

// ---------------------------------------------------------------------------
// Bilinear 2x upsample, align_corners=True.
// ---------------------------------------------------------------------------
__global__ void up2_kernel(const float* __restrict__ in, float* __restrict__ out,
                           int Hi, int Wi) {
  const int Ho = 2 * Hi, Wo = 2 * Wi;
  const int ox = blockIdx.x * 16 + threadIdx.x;
  const int oy = blockIdx.y * 16 + threadIdx.y;
  const int bc = blockIdx.z;
  const float sy = (float)((double)(Hi - 1) / (double)(Ho - 1));
  const float sx = (float)((double)(Wi - 1) / (double)(Wo - 1));
  float fy = oy * sy, fx = ox * sx;
  int y0 = (int)floorf(fy); int y1 = min(y0 + 1, Hi - 1);
  int x0 = (int)floorf(fx); int x1 = min(x0 + 1, Wi - 1);
  float wy = fy - (float)y0, wx = fx - (float)x0;
  const float* p = in + bc * Hi * Wi;
  float a00 = p[y0 * Wi + x0], a01 = p[y0 * Wi + x1];
  float a10 = p[y1 * Wi + x0], a11 = p[y1 * Wi + x1];
  float r0 = a00 * (1.f - wy) + a10 * wy;
  float r1 = a01 * (1.f - wy) + a11 * wy;
  out[(bc * Ho + oy) * Wo + ox] = r0 * (1.f - wx) + r1 * wx;
}

// ---------------------------------------------------------------------------
// FCAS on the 64x64 channel x4[0,1].
// ---------------------------------------------------------------------------
__global__ void fcas_count_kernel(const float* __restrict__ ch,
                                  const float* __restrict__ w,
                                  const float* __restrict__ bb,
                                  float* __restrict__ scratch) {
  const int H = 64, W = 64, N = H * W;
  __shared__ float vals[N];
  for (int i = threadIdx.x; i < N; i += blockDim.x) vals[i] = ch[i];
  __syncthreads();
  int idx = blockIdx.x * blockDim.x + threadIdx.x;
  if (idx >= N) return;
  float v = vals[idx];
  int p = 0, n = 0, e = 0;
  for (int k = 0; k < N; ++k) {
    float u = vals[k];
    p += (u > v);
    n += (u == v);
    e += (u < v);
  }
  float val = ((float)p * w[0] + bb[0] + (float)n * w[1] + bb[1] +
               (float)e * w[2] + bb[2]) / 3.0f;
  int i = idx >> 6, j = idx & 63;
  bool interior = (i >= 1) && (i <= H - 2) && (j >= 1) && (j <= W - 2);
  scratch[idx] = interior ? val : v;
}

__global__ void fcas_copy_kernel(const float* __restrict__ scratch,
                                 float* __restrict__ ch) {
  int i = blockIdx.x * 256 + threadIdx.x;
  if (i < 4096) ch[i] = scratch[i];
}

// ---------------------------------------------------------------------------
extern "C" void kernel_launch(void* const* d_in, const int* in_sizes, int n_in,
                              void* d_out, int out_size, void* d_ws, size_t ws_size,
                              hipStream_t stream) {
  const float* x      = (const float*)d_in[0];
  const float* w_inc  = (const float*)d_in[1];
  const float* b_inc  = (const float*)d_in[2];
  const float* g_inc  = (const float*)d_in[3];
  const float* a_inc  = (const float*)d_in[4];
  const float* w_d1   = (const float*)d_in[5];
  const float* b_d1   = (const float*)d_in[6];
  const float* g_d1   = (const float*)d_in[7];
  const float* a_d1   = (const float*)d_in[8];
  const float* w_d2   = (const float*)d_in[9];
  const float* b_d2   = (const float*)d_in[10];
  const float* g_d2   = (const float*)d_in[11];
  const float* a_d2   = (const float*)d_in[12];
  const float* w_d3   = (const float*)d_in[13];
  const float* b_d3   = (const float*)d_in[14];
  const float* g_d3   = (const float*)d_in[15];
  const float* a_d3   = (const float*)d_in[16];
  const float* w_u2   = (const float*)d_in[17];
  const float* b_u2   = (const float*)d_in[18];
  const float* g_u2   = (const float*)d_in[19];
  const float* a_u2   = (const float*)d_in[20];
  const float* w_u3   = (const float*)d_in[21];
  const float* b_u3   = (const float*)d_in[22];
  const float* g_u3   = (const float*)d_in[23];
  const float* a_u3   = (const float*)d_in[24];
  const float* w_u4   = (const float*)d_in[25];
  const float* b_u4   = (const float*)d_in[26];
  const float* g_u4   = (const float*)d_in[27];
  const float* a_u4   = (const float*)d_in[28];
  const float* w_out  = (const float*)d_in[29];
  const float* b_out  = (const float*)d_in[30];
  const float* fcas_w = (const float*)d_in[31];
  const float* fcas_b = (const float*)d_in[32];

  float* ws = (float*)d_ws;
  // workspace layout (floats)
  float* x1 = ws;                      // 16,777,216
  float* x2 = x1 + 16777216;           //  8,388,608
  float* x3 = x2 + 8388608;            //  4,194,304
  float* x4 = x3 + 4194304;            //  1,048,576
  float* up = x4 + 1048576;            // 16,777,216
  float* uo = up + 16777216;           //  4,194,304
  float* fs = uo + 4194304;            //  4,096
  // folded weights
  float* wp = fs + 4096;
  float* wf_inc = wp;                  // 8*3*9    = 216
  float* wf_d1  = wf_inc + 216;        // 16*8*9   = 1152
  float* wf_d2  = wf_d1 + 1152;        // 32*16*9  = 4608
  float* wf_d3  = wf_d2 + 4608;        // 32*32*9  = 9216
  float* wf_u2  = wf_d3 + 9216;        // 16*64*9  = 9216
  float* wf_u3  = wf_u2 + 9216;        // 8*32*9   = 2304
  float* wf_u4  = wf_u3 + 2304;        // 4*16*9   = 576
  float* bfp    = wf_u4 + 576;
  float* bf_inc = bfp;                 // 8
  float* bf_d1  = bf_inc + 8;          // 16
  float* bf_d2  = bf_d1 + 16;          // 32
  float* bf_d3  = bf_d2 + 32;          // 32
  float* bf_u2  = bf_d3 + 32;          // 16
  float* bf_u3  = bf_u2 + 16;          // 8
  float* bf_u4  = bf_u3 + 8;           // 4
  float* outp = (float*)d_out;

  // ---- prefold BN into weights (one launch, all layers) ----
  AllP A;
  A.L[0] = {w_inc, b_inc, g_inc, a_inc, wf_inc, bf_inc, 8, 3};
  A.L[1] = {w_d1, b_d1, g_d1, a_d1, wf_d1, bf_d1, 16, 8};
  A.L[2] = {w_d2, b_d2, g_d2, a_d2, wf_d2, bf_d2, 32, 16};
  A.L[3] = {w_d3, b_d3, g_d3, a_d3, wf_d3, bf_d3, 32, 32};
  A.L[4] = {w_u2, b_u2, g_u2, a_u2, wf_u2, bf_u2, 16, 64};
  A.L[5] = {w_u3, b_u3, g_u3, a_u3, wf_u3, bf_u3, 8, 32};
  A.L[6] = {w_u4, b_u4, g_u4, a_u4, wf_u4, bf_u4, 4, 16};
  prefold_kernel<<<dim3(36, 7), dim3(256), 0, stream>>>(A);

  dim3 blk(256);
  dim3 blk2(16, 16);

  // inc: 3->8 @512
  conv3x3_cbr<3, 0, 8, 1, false, false><<<dim3(32, 32, 8), blk, 0, stream>>>(
      x, nullptr, wf_inc, bf_inc, nullptr, nullptr, x1, 512, 512);
  // d1: pool -> 8->16 @256
  conv3x3_cbr<8, 0, 16, 1, true, false><<<dim3(16, 16, 8), blk, 0, stream>>>(
      x1, nullptr, wf_d1, bf_d1, nullptr, nullptr, x2, 256, 256);
  // d2: pool -> 16->32 @128 (OSPLIT=2 -> 1024 blocks)
  conv3x3_cbr<16, 0, 16, 2, true, false><<<dim3(8, 8, 16), blk, 0, stream>>>(
      x2, nullptr, wf_d2, bf_d2, nullptr, nullptr, x3, 128, 128);
  // d3: pool -> 32->32 @64 (OSPLIT=4 -> 512 blocks)
  conv3x3_cbr<32, 0, 8, 4, true, false><<<dim3(4, 4, 32), blk, 0, stream>>>(
      x3, nullptr, wf_d3, bf_d3, nullptr, nullptr, x4, 64, 64);
  // FCAS on x4[0,1]
  fcas_count_kernel<<<dim3(16), blk, 0, stream>>>(x4 + 4096, fcas_w, fcas_b, fs);
  fcas_copy_kernel<<<dim3(16), blk, 0, stream>>>(fs, x4 + 4096);
  // up2(x4) 64->128
  up2_kernel<<<dim3(8, 8, 256), blk2, 0, stream>>>(x4, up, 64, 64);
  // u2: cat(x3, up) 64->16 @128 (OSPLIT=2 -> 1024 blocks)
  conv3x3_cbr<32, 32, 8, 2, false, false><<<dim3(8, 8, 16), blk, 0, stream>>>(
      x3, up, wf_u2, bf_u2, nullptr, nullptr, uo, 128, 128);
  // up2(u2out) 128->256
  up2_kernel<<<dim3(16, 16, 128), blk2, 0, stream>>>(uo, up, 128, 128);
  // u3: cat(x2, up) 32->8 @256
  conv3x3_cbr<16, 16, 8, 1, false, false><<<dim3(16, 16, 8), blk, 0, stream>>>(
      x2, up, wf_u3, bf_u3, nullptr, nullptr, uo, 256, 256);
  // up2(u3out) 256->512
  up2_kernel<<<dim3(32, 32, 64), blk2, 0, stream>>>(uo, up, 256, 256);
  // u4: cat(x1, up) 16->4 @512, fused 1x1 conv + sigmoid
  conv3x3_cbr<8, 8, 4, 1, false, true><<<dim3(32, 32, 8), blk, 0, stream>>>(
      x1, up, wf_u4, bf_u4, w_out, b_out, outp, 512, 512);
}

// Round 3
// 775.459 us; speedup vs baseline: 1.5973x; 1.3176x over previous
//
#include <hip/hip_runtime.h>
#include <hip/hip_bf16.h>

#define BN_RSQ 0.9999950000374997f  // 1/sqrt(1+1e-5)

// ---------------------------------------------------------------------------
// Prefold BN into conv weights: wf = w*g*rsq, bf = b*g*rsq + a.
// ---------------------------------------------------------------------------
struct LayerP {
  const float* w; const float* b; const float* g; const float* a;
  float* wf; float* bf; int cout; int cin;
};
struct AllP { LayerP L[7]; };

__global__ void prefold_kernel(AllP A) {
  LayerP p = A.L[blockIdx.y];
  int n = p.cout * p.cin * 9;
  int i = blockIdx.x * 256 + threadIdx.x;
  if (i < n) {
    int o = i / (p.cin * 9);
    p.wf[i] = p.w[i] * p.g[o] * BN_RSQ;
  }
  if (i < p.cout) p.bf[i] = p.b[i] * p.g[i] * BN_RSQ + p.a[i];
}

// ---------------------------------------------------------------------------
// 3x3 SAME conv (+folded BN) + ReLU, 4-px-per-thread x-blocking.
//   Tile: 64x16 output px per block (256 threads; thread = 4 consecutive x).
//   - CIN1 channels from in1 (optionally 2x2-maxpooled on the fly: POOL_IN),
//     CIN2 channels from in2 (optionally bilinear-2x-upsampled on the fly:
//     UP_IN2, align_corners=True, in2 dims [B,CIN2,H/2,W/2]).
//   - OSPLIT: output-channel split across blocks (blockIdx.z = og*8 + batch).
//   - FUSE_OUT: 1x1 conv + sigmoid epilogue (requires OSPLIT==1).
// LDS tile row stride 68 floats: 16B-aligned float4 reads, bank pattern
// (4tx+4ty)%32 = perfect 2-way (free on gfx950). Weights staged to LDS and
// read as uniform-address broadcast float4 (no scalar loads in inner loop).
// ---------------------------------------------------------------------------
template <int CIN1, int CIN2, int COUTG, int OSPLIT, bool POOL_IN, bool UP_IN2,
          bool FUSE_OUT>
__launch_bounds__(256)
__global__ void conv3x3_cbr(const float* __restrict__ in1,
                            const float* __restrict__ in2,
                            const float* __restrict__ wf,
                            const float* __restrict__ bf,
                            const float* __restrict__ wout,
                            const float* __restrict__ bout,
                            float* __restrict__ out, int H, int W) {
  constexpr int CIN = CIN1 + CIN2;
  constexpr int COUT = COUTG * OSPLIT;
  constexpr int CHUNK = (CIN < 4) ? CIN : 4;
  constexpr int XT = 66;   // tile x extent (64 + 2 halo)
  constexpr int XS = 68;   // tile x stride (aligned, conflict-free)
  constexpr int YT = 18;   // tile y extent (16 + 2 halo)
  constexpr int WS = 12;   // weight stride (float4-friendly)

  __shared__ float tile[CHUNK][YT][XS];
  __shared__ float wsm[COUTG * CHUNK * WS];

  const int tid = threadIdx.x;
  const int tx4 = (tid & 15) * 4;
  const int ty = tid >> 4;           // 0..15
  const int gx0 = blockIdx.x * 64;
  const int gy0 = blockIdx.y * 16;
  const int b = blockIdx.z & 7;
  const int og = blockIdx.z >> 3;
  const int obase = og * COUTG;

  float acc[COUTG][4];
#pragma unroll
  for (int o = 0; o < COUTG; ++o)
#pragma unroll
    for (int i = 0; i < 4; ++i) acc[o][i] = 0.f;

  for (int cc = 0; cc < CIN; cc += CHUNK) {
    __syncthreads();
    // ---- stage weights for this chunk ----
    for (int idx = tid; idx < COUTG * CHUNK * 9; idx += 256) {
      int o = idx / (CHUNK * 9);
      int r = idx - o * (CHUNK * 9);
      int c = r / 9;
      int t = r - c * 9;
      wsm[(o * CHUNK + c) * WS + t] = wf[((obase + o) * CIN + cc + c) * 9 + t];
    }
    // ---- stage input tile (halo 66x18 per channel) ----
    for (int idx = tid; idx < CHUNK * YT * XT; idx += 256) {
      int c = idx / (YT * XT);
      int r = idx - c * (YT * XT);
      int yy = r / XT;
      int xx = r - yy * XT;
      int iy = gy0 + yy - 1;
      int ix = gx0 + xx - 1;
      int cg = cc + c;
      float v = 0.f;
      if (iy >= 0 && iy < H && ix >= 0 && ix < W) {
        if (CIN2 == 0 || cg < CIN1) {
          const int cb = b * CIN1 + cg;
          if (POOL_IN) {
            const float* p = in1 + (cb * (2 * H) + 2 * iy) * (2 * W) + 2 * ix;
            float v0 = p[0], v1 = p[1], v2 = p[2 * W], v3 = p[2 * W + 1];
            v = fmaxf(fmaxf(v0, v1), fmaxf(v2, v3));
          } else {
            v = in1[(cb * H + iy) * W + ix];
          }
        } else {
          const int cb = b * CIN2 + (cg - CIN1);
          if (UP_IN2) {
            const int Hi = H >> 1, Wi = W >> 1;
            const float sy = (float)(Hi - 1) / (float)(H - 1);
            const float sx = (float)(Wi - 1) / (float)(W - 1);
            float fy = iy * sy, fx = ix * sx;
            int y0 = (int)fy; int y1 = min(y0 + 1, Hi - 1);
            int x0 = (int)fx; int x1 = min(x0 + 1, Wi - 1);
            float wy = fy - (float)y0, wx = fx - (float)x0;
            const float* p = in2 + cb * Hi * Wi;
            float a00 = p[y0 * Wi + x0], a01 = p[y0 * Wi + x1];
            float a10 = p[y1 * Wi + x0], a11 = p[y1 * Wi + x1];
            float r0 = a00 * (1.f - wy) + a10 * wy;
            float r1 = a01 * (1.f - wy) + a11 * wy;
            v = r0 * (1.f - wx) + r1 * wx;
          } else {
            v = in2[(cb * H + iy) * W + ix];
          }
        }
      }
      tile[c][yy][xx] = v;
    }
    __syncthreads();
    // ---- accumulate: vector LDS reads + FMAs ----
#pragma unroll
    for (int c = 0; c < CHUNK; ++c) {
      float r[3][6];
#pragma unroll
      for (int dy = 0; dy < 3; ++dy) {
        const float* p = &tile[c][ty + dy][tx4];
        float4 a4 = *(const float4*)p;        // 16B-aligned
        float2 b2 = *(const float2*)(p + 4);  // 8B-aligned
        r[dy][0] = a4.x; r[dy][1] = a4.y; r[dy][2] = a4.z; r[dy][3] = a4.w;
        r[dy][4] = b2.x; r[dy][5] = b2.y;
      }
#pragma unroll
      for (int o = 0; o < COUTG; ++o) {
        const float4* wp = (const float4*)&wsm[(o * CHUNK + c) * WS];
        float4 wa = wp[0];
        float4 wb = wp[1];
        float w8 = wsm[(o * CHUNK + c) * WS + 8];
#pragma unroll
        for (int i = 0; i < 4; ++i) {
          float s = acc[o][i];
          s = fmaf(r[0][i + 0], wa.x, s);
          s = fmaf(r[0][i + 1], wa.y, s);
          s = fmaf(r[0][i + 2], wa.z, s);
          s = fmaf(r[1][i + 0], wa.w, s);
          s = fmaf(r[1][i + 1], wb.x, s);
          s = fmaf(r[1][i + 2], wb.y, s);
          s = fmaf(r[2][i + 0], wb.z, s);
          s = fmaf(r[2][i + 1], wb.w, s);
          s = fmaf(r[2][i + 2], w8, s);
          acc[o][i] = s;
        }
      }
    }
  }

  const int oy = gy0 + ty;
  const int ox = gx0 + tx4;
  if (FUSE_OUT) {
    float4 sv;
    float* s = (float*)&sv;
#pragma unroll
    for (int i = 0; i < 4; ++i) s[i] = bout[0];
#pragma unroll
    for (int o = 0; o < COUTG; ++o) {
      float bo = bf[obase + o], wo = wout[o];
#pragma unroll
      for (int i = 0; i < 4; ++i) {
        float rr = fmaxf(acc[o][i] + bo, 0.f);
        s[i] = fmaf(rr, wo, s[i]);
      }
    }
#pragma unroll
    for (int i = 0; i < 4; ++i) s[i] = 1.f / (1.f + __expf(-s[i]));
    *(float4*)&out[(b * H + oy) * W + ox] = sv;
  } else {
#pragma unroll
    for (int o = 0; o < COUTG; ++o) {
      float bo = bf[obase + o];
      float4 rv;
      float* r = (float*)&rv;
#pragma unroll
      for (int i = 0; i < 4; ++i) r[i] = fmaxf(acc[o][i] + bo, 0.f);
      *(float4*)&out[((b * COUT + obase + o) * H + oy) * W + ox] = rv;
    }
  }
}

// ---------------------------------------------------------------------------
// FCAS on the 64x64 channel x4[0,1].
// ---------------------------------------------------------------------------
__global__ void fcas_count_kernel(const float* __restrict__ ch,
                                  const float* __restrict__ w,
                                  const float* __restrict__ bb,
                                  float* __restrict__ scratch) {
  const int H = 64, W = 64, N = H * W;
  __shared__ float vals[N];
  for (int i = threadIdx.x; i < N; i += blockDim.x) vals[i] = ch[i];
  __syncthreads();
  int idx = blockIdx.x * blockDim.x + threadIdx.x;
  if (idx >= N) return;
  float v = vals[idx];
  int p = 0, n = 0, e = 0;
  for (int k = 0; k < N; ++k) {
    float u = vals[k];
    p += (u > v);
    n += (u == v);
    e += (u < v);
  }
  float val = ((float)p * w[0] + bb[0] + (float)n * w[1] + bb[1] +
               (float)e * w[2] + bb[2]) / 3.0f;
  int i = idx >> 6, j = idx & 63;
  bool interior = (i >= 1) && (i <= H - 2) && (j >= 1) && (j <= W - 2);
  scratch[idx] = interior ? val : v;
}

__global__ void fcas_copy_kernel(const float* __restrict__ scratch,
                                 float* __restrict__ ch) {
  int i = blockIdx.x * 256 + threadIdx.x;
  if (i < 4096) ch[i] = scratch[i];
}

// ---------------------------------------------------------------------------
extern "C" void kernel_launch(void* const* d_in, const int* in_sizes, int n_in,
                              void* d_out, int out_size, void* d_ws, size_t ws_size,
                              hipStream_t stream) {
  const float* x      = (const float*)d_in[0];
  const float* w_inc  = (const float*)d_in[1];
  const float* b_inc  = (const float*)d_in[2];
  const float* g_inc  = (const float*)d_in[3];
  const float* a_inc  = (const float*)d_in[4];
  const float* w_d1   = (const float*)d_in[5];
  const float* b_d1   = (const float*)d_in[6];
  const float* g_d1   = (const float*)d_in[7];
  const float* a_d1   = (const float*)d_in[8];
  const float* w_d2   = (const float*)d_in[9];
  const float* b_d2   = (const float*)d_in[10];
  const float* g_d2   = (const float*)d_in[11];
  const float* a_d2   = (const float*)d_in[12];
  const float* w_d3   = (const float*)d_in[13];
  const float* b_d3   = (const float*)d_in[14];
  const float* g_d3   = (const float*)d_in[15];
  const float* a_d3   = (const float*)d_in[16];
  const float* w_u2   = (const float*)d_in[17];
  const float* b_u2   = (const float*)d_in[18];
  const float* g_u2   = (const float*)d_in[19];
  const float* a_u2   = (const float*)d_in[20];
  const float* w_u3   = (const float*)d_in[21];
  const float* b_u3   = (const float*)d_in[22];
  const float* g_u3   = (const float*)d_in[23];
  const float* a_u3   = (const float*)d_in[24];
  const float* w_u4   = (const float*)d_in[25];
  const float* b_u4   = (const float*)d_in[26];
  const float* g_u4   = (const float*)d_in[27];
  const float* a_u4   = (const float*)d_in[28];
  const float* w_out  = (const float*)d_in[29];
  const float* b_out  = (const float*)d_in[30];
  const float* fcas_w = (const float*)d_in[31];
  const float* fcas_b = (const float*)d_in[32];

  float* ws = (float*)d_ws;
  float* x1  = ws;                     // 16,777,216
  float* x2  = x1 + 16777216;          //  8,388,608
  float* x3  = x2 + 8388608;           //  4,194,304
  float* x4  = x3 + 4194304;           //  1,048,576
  float* uo2 = x4 + 1048576;           //  2,097,152  (u2 out, 128^2 x16ch)
  float* uo3 = uo2 + 2097152;          //  4,194,304  (u3 out, 256^2 x8ch)
  float* fs  = uo3 + 4194304;          //  4,096
  float* wfp = fs + 4096;
  float* wf_inc = wfp;                 // 216
  float* wf_d1  = wf_inc + 216;        // 1152
  float* wf_d2  = wf_d1 + 1152;        // 4608
  float* wf_d3  = wf_d2 + 4608;        // 9216
  float* wf_u2  = wf_d3 + 9216;        // 9216
  float* wf_u3  = wf_u2 + 9216;        // 2304
  float* wf_u4  = wf_u3 + 2304;        // 576
  float* bf_inc = wf_u4 + 576;         // 8
  float* bf_d1  = bf_inc + 8;          // 16
  float* bf_d2  = bf_d1 + 16;          // 32
  float* bf_d3  = bf_d2 + 32;          // 32
  float* bf_u2  = bf_d3 + 32;          // 16
  float* bf_u3  = bf_u2 + 16;          // 8
  float* bf_u4  = bf_u3 + 8;           // 4
  float* outp = (float*)d_out;

  AllP A;
  A.L[0] = {w_inc, b_inc, g_inc, a_inc, wf_inc, bf_inc, 8, 3};
  A.L[1] = {w_d1, b_d1, g_d1, a_d1, wf_d1, bf_d1, 16, 8};
  A.L[2] = {w_d2, b_d2, g_d2, a_d2, wf_d2, bf_d2, 32, 16};
  A.L[3] = {w_d3, b_d3, g_d3, a_d3, wf_d3, bf_d3, 32, 32};
  A.L[4] = {w_u2, b_u2, g_u2, a_u2, wf_u2, bf_u2, 16, 64};
  A.L[5] = {w_u3, b_u3, g_u3, a_u3, wf_u3, bf_u3, 8, 32};
  A.L[6] = {w_u4, b_u4, g_u4, a_u4, wf_u4, bf_u4, 4, 16};
  prefold_kernel<<<dim3(36, 7), dim3(256), 0, stream>>>(A);

  dim3 blk(256);

  // inc: 3->8 @512
  conv3x3_cbr<3, 0, 8, 1, false, false, false><<<dim3(8, 32, 8), blk, 0, stream>>>(
      x, nullptr, wf_inc, bf_inc, nullptr, nullptr, x1, 512, 512);
  // d1: pool(x1) -> 8->16 @256 (OSPLIT=2)
  conv3x3_cbr<8, 0, 8, 2, true, false, false><<<dim3(4, 16, 16), blk, 0, stream>>>(
      x1, nullptr, wf_d1, bf_d1, nullptr, nullptr, x2, 256, 256);
  // d2: pool(x2) -> 16->32 @128 (OSPLIT=4)
  conv3x3_cbr<16, 0, 8, 4, true, false, false><<<dim3(2, 8, 32), blk, 0, stream>>>(
      x2, nullptr, wf_d2, bf_d2, nullptr, nullptr, x3, 128, 128);
  // d3: pool(x3) -> 32->32 @64 (OSPLIT=8)
  conv3x3_cbr<32, 0, 4, 8, true, false, false><<<dim3(1, 4, 64), blk, 0, stream>>>(
      x3, nullptr, wf_d3, bf_d3, nullptr, nullptr, x4, 64, 64);
  // FCAS on x4[0,1]
  fcas_count_kernel<<<dim3(16), blk, 0, stream>>>(x4 + 4096, fcas_w, fcas_b, fs);
  fcas_copy_kernel<<<dim3(16), blk, 0, stream>>>(fs, x4 + 4096);
  // u2: cat(x3, up2(x4)) 64->16 @128 (OSPLIT=4, fused upsample)
  conv3x3_cbr<32, 32, 4, 4, false, true, false><<<dim3(2, 8, 32), blk, 0, stream>>>(
      x3, x4, wf_u2, bf_u2, nullptr, nullptr, uo2, 128, 128);
  // u3: cat(x2, up2(u2out)) 32->8 @256 (OSPLIT=2, fused upsample)
  conv3x3_cbr<16, 16, 4, 2, false, true, false><<<dim3(4, 16, 16), blk, 0, stream>>>(
      x2, uo2, wf_u3, bf_u3, nullptr, nullptr, uo3, 256, 256);
  // u4: cat(x1, up2(u3out)) 16->4 @512, fused 1x1 conv + sigmoid + upsample
  conv3x3_cbr<8, 8, 4, 1, false, true, true><<<dim3(8, 32, 8), blk, 0, stream>>>(
      x1, uo3, wf_u4, bf_u4, w_out, b_out, outp, 512, 512);
}